// Round 1
// baseline (284.811 us; speedup 1.0000x reference)
//
#include <hip/hip_runtime.h>
#include <stdint.h>

typedef float f32x4 __attribute__((ext_vector_type(4)));
typedef short s16x8 __attribute__((ext_vector_type(8)));

#define MFMA(a, b, c) __builtin_amdgcn_mfma_f32_16x16x32_bf16((a), (b), (c), 0, 0, 0)

__device__ __forceinline__ unsigned short f32_to_bf16(float f) {
    union { float f; uint32_t u; } v; v.f = f;
    uint32_t r = v.u + 0x7FFFu + ((v.u >> 16) & 1u);
    return (unsigned short)(r >> 16);
}
__device__ __forceinline__ float bf16_to_f32(unsigned short h) {
    union { float f; uint32_t u; } v; v.u = ((uint32_t)h) << 16;
    return v.f;
}

// ---------------------------------------------------------------------------
// Kernel 1: qkv = x @ w_qkv^T   (fp32 in, fp32 out; split-bf16 3xMFMA inside)
// X [4096,768], W [2304,768], OUT [4096,2304]. grid (32,18), block 256.
// ---------------------------------------------------------------------------
__global__ __launch_bounds__(256) void qkv_gemm(const float* __restrict__ X,
                                                const float* __restrict__ W,
                                                float* __restrict__ OUT) {
    __shared__ short Ah[128 * 40], Al[128 * 40], Bh[128 * 40], Bl[128 * 40];
    const int t = threadIdx.x;
    const int lane = t & 63, wv = t >> 6;
    const int wm = (wv >> 1) * 64, wn = (wv & 1) * 64;
    const int r = lane & 15, g = lane >> 4;
    const int bm = blockIdx.x, bn = blockIdx.y;

    f32x4 acc[4][4];
#pragma unroll
    for (int i = 0; i < 4; ++i)
#pragma unroll
        for (int j = 0; j < 4; ++j) acc[i][j] = (f32x4)0.0f;

    const int srow = t >> 1;
    const int sk0 = (t & 1) * 16;

    for (int ks = 0; ks < 768; ks += 32) {
        // stage x-tile and w-tile (128x32 each), split into bf16 hi/lo
        {
            const float* ax = X + (size_t)(bm * 128 + srow) * 768 + ks + sk0;
            const float* bx = W + (size_t)(bn * 128 + srow) * 768 + ks + sk0;
            short ah[16], al[16], bh2[16], bl2[16];
#pragma unroll
            for (int j = 0; j < 16; j += 4) {
                f32x4 av = *(const f32x4*)(ax + j);
                f32x4 bv = *(const f32x4*)(bx + j);
#pragma unroll
                for (int q = 0; q < 4; ++q) {
                    unsigned short h1 = f32_to_bf16(av[q]);
                    ah[j + q] = (short)h1;
                    al[j + q] = (short)f32_to_bf16(av[q] - bf16_to_f32(h1));
                    unsigned short h2 = f32_to_bf16(bv[q]);
                    bh2[j + q] = (short)h2;
                    bl2[j + q] = (short)f32_to_bf16(bv[q] - bf16_to_f32(h2));
                }
            }
            *(s16x8*)&Ah[srow * 40 + sk0]     = *(s16x8*)&ah[0];
            *(s16x8*)&Ah[srow * 40 + sk0 + 8] = *(s16x8*)&ah[8];
            *(s16x8*)&Al[srow * 40 + sk0]     = *(s16x8*)&al[0];
            *(s16x8*)&Al[srow * 40 + sk0 + 8] = *(s16x8*)&al[8];
            *(s16x8*)&Bh[srow * 40 + sk0]     = *(s16x8*)&bh2[0];
            *(s16x8*)&Bh[srow * 40 + sk0 + 8] = *(s16x8*)&bh2[8];
            *(s16x8*)&Bl[srow * 40 + sk0]     = *(s16x8*)&bl2[0];
            *(s16x8*)&Bl[srow * 40 + sk0 + 8] = *(s16x8*)&bl2[8];
        }
        __syncthreads();

        const int koff = g * 8;
        s16x8 a_h[4], a_l[4], b_h[4], b_l[4];
#pragma unroll
        for (int mf = 0; mf < 4; ++mf) {
            a_h[mf] = *(s16x8*)&Ah[(wm + mf * 16 + r) * 40 + koff];
            a_l[mf] = *(s16x8*)&Al[(wm + mf * 16 + r) * 40 + koff];
        }
#pragma unroll
        for (int nf = 0; nf < 4; ++nf) {
            b_h[nf] = *(s16x8*)&Bh[(wn + nf * 16 + r) * 40 + koff];
            b_l[nf] = *(s16x8*)&Bl[(wn + nf * 16 + r) * 40 + koff];
        }
#pragma unroll
        for (int mf = 0; mf < 4; ++mf)
#pragma unroll
            for (int nf = 0; nf < 4; ++nf) {
                acc[mf][nf] = MFMA(a_h[mf], b_h[nf], acc[mf][nf]);
                acc[mf][nf] = MFMA(a_h[mf], b_l[nf], acc[mf][nf]);
                acc[mf][nf] = MFMA(a_l[mf], b_h[nf], acc[mf][nf]);
            }
        __syncthreads();
    }

#pragma unroll
    for (int mf = 0; mf < 4; ++mf)
#pragma unroll
        for (int nf = 0; nf < 4; ++nf) {
            const int row = bm * 128 + wm + mf * 16 + g * 4;
            const int col = bn * 128 + wn + nf * 16 + r;
#pragma unroll
            for (int v = 0; v < 4; ++v)
                OUT[(size_t)(row + v) * 2304 + col] = acc[mf][nf][v];
        }
}

// ---------------------------------------------------------------------------
// Kernel 2: permute qkv[b,n, c*768 + d*12 + h] -> per-head [b,h,n,64] arrays.
// Q is pre-scaled by temperature (=8) and split hi/lo; K split hi/lo; V bf16.
// ---------------------------------------------------------------------------
__global__ void permute_split(const float* __restrict__ QKV,
                              unsigned short* __restrict__ Qh, unsigned short* __restrict__ Ql,
                              unsigned short* __restrict__ Kh, unsigned short* __restrict__ Kl,
                              unsigned short* __restrict__ Vb) {
    const int tid = blockIdx.x * 256 + threadIdx.x;  // 3*2*12*2048*64 total
    const int d = tid & 63;
    const int n = (tid >> 6) & 2047;
    const int rem = tid >> 17;           // comp*24 + b*12 + h, 0..71
    const int h = rem % 12;
    const int cb = rem / 12;             // comp*2 + b
    const int b = cb & 1;
    const int comp = cb >> 1;

    float v = QKV[(size_t)(b * 2048 + n) * 2304 + comp * 768 + d * 12 + h];
    const size_t o = ((size_t)((b * 12 + h) * 2048 + n)) * 64 + d;
    if (comp == 0) {
        v *= 8.0f;  // fold temperature = sqrt(d_k) (reference MULTIPLIES)
        unsigned short hi = f32_to_bf16(v);
        Qh[o] = hi;
        Ql[o] = f32_to_bf16(v - bf16_to_f32(hi));
    } else if (comp == 1) {
        unsigned short hi = f32_to_bf16(v);
        Kh[o] = hi;
        Kl[o] = f32_to_bf16(v - bf16_to_f32(hi));
    } else {
        Vb[o] = f32_to_bf16(v);
    }
}

// ---------------------------------------------------------------------------
// Kernel 3: flash attention per (b,h). block = 128 Q rows (4 waves x 32 rows),
// KV tiles of 64. Split-bf16 QK^T (3 MFMA), fp32 online softmax, bf16 PV.
// grid 24*16 = 384, block 256.
// ---------------------------------------------------------------------------
__global__ __launch_bounds__(256) void attn_kernel(
    const unsigned short* __restrict__ Qh, const unsigned short* __restrict__ Ql,
    const unsigned short* __restrict__ Kh, const unsigned short* __restrict__ Kl,
    const unsigned short* __restrict__ Vb, unsigned short* __restrict__ AO) {
    __shared__ short Khs[64 * 72], Kls[64 * 72], VT[64 * 72];
    __shared__ short Pl[4][32 * 72];

    const int t = threadIdx.x;
    const int lane = t & 63, wv = t >> 6;
    const int r = lane & 15, g = lane >> 4;
    const int bh = blockIdx.x >> 4;   // 0..23
    const int qb = blockIdx.x & 15;
    const size_t headoff = (size_t)bh * 2048 * 64;
    const int q0 = qb * 128 + wv * 32;

    // Q fragments (A-layout): lane r+16g holds Q[q0+qf*16+r][kc*32+g*8 .. +7]
    s16x8 qh[2][2], ql[2][2];
#pragma unroll
    for (int qf = 0; qf < 2; ++qf)
#pragma unroll
        for (int kc = 0; kc < 2; ++kc) {
            const size_t off = headoff + (size_t)(q0 + qf * 16 + r) * 64 + kc * 32 + g * 8;
            qh[qf][kc] = *(const s16x8*)(Qh + off);
            ql[qf][kc] = *(const s16x8*)(Ql + off);
        }

    f32x4 o_acc[2][4];
    float m_run[2][4], l_run[2][4];
#pragma unroll
    for (int qf = 0; qf < 2; ++qf) {
#pragma unroll
        for (int df = 0; df < 4; ++df) o_acc[qf][df] = (f32x4)0.0f;
#pragma unroll
        for (int v = 0; v < 4; ++v) { m_run[qf][v] = -1e30f; l_run[qf][v] = 0.0f; }
    }

    for (int kt = 0; kt < 32; ++kt) {
        // ---- stage K(hi/lo) row-major [64][72-pad], V transposed+swizzled
#pragma unroll
        for (int it = 0; it < 2; ++it) {
            const int row = (t >> 3) + it * 32;
            const int d0 = (t & 7) * 8;
            const size_t goff = headoff + (size_t)(kt * 64 + row) * 64 + d0;
            s16x8 kh = *(const s16x8*)(Kh + goff);
            s16x8 kl = *(const s16x8*)(Kl + goff);
            s16x8 vv = *(const s16x8*)(Vb + goff);
            *(s16x8*)&Khs[row * 72 + d0] = kh;
            *(s16x8*)&Kls[row * 72 + d0] = kl;
#pragma unroll
            for (int j = 0; j < 8; ++j) {
                const int dd = d0 + j;
                const int sw = (((dd >> 3) ^ dd) & 7) << 3;
                VT[dd * 72 + (row ^ sw)] = vv[j];
            }
        }
        __syncthreads();

        // ---- S = Q K^T  (3-pass split)
        f32x4 s[2][4];
#pragma unroll
        for (int qf = 0; qf < 2; ++qf)
#pragma unroll
            for (int cf = 0; cf < 4; ++cf) s[qf][cf] = (f32x4)0.0f;

#pragma unroll
        for (int kc = 0; kc < 2; ++kc) {
            const int koff = kc * 32 + g * 8;
            s16x8 kbh[4], kbl[4];
#pragma unroll
            for (int cf = 0; cf < 4; ++cf) {
                kbh[cf] = *(s16x8*)&Khs[(cf * 16 + r) * 72 + koff];
                kbl[cf] = *(s16x8*)&Kls[(cf * 16 + r) * 72 + koff];
            }
#pragma unroll
            for (int qf = 0; qf < 2; ++qf)
#pragma unroll
                for (int cf = 0; cf < 4; ++cf) {
                    s[qf][cf] = MFMA(qh[qf][kc], kbh[cf], s[qf][cf]);
                    s[qf][cf] = MFMA(qh[qf][kc], kbl[cf], s[qf][cf]);
                    s[qf][cf] = MFMA(ql[qf][kc], kbh[cf], s[qf][cf]);
                }
        }

        // ---- online softmax (rows live at reg v + lane-group g)
#pragma unroll
        for (int qf = 0; qf < 2; ++qf) {
#pragma unroll
            for (int v = 0; v < 4; ++v) {
                float mx = fmaxf(fmaxf(s[qf][0][v], s[qf][1][v]),
                                 fmaxf(s[qf][2][v], s[qf][3][v]));
#pragma unroll
                for (int msk = 1; msk < 16; msk <<= 1) mx = fmaxf(mx, __shfl_xor(mx, msk));
                const float mo = m_run[qf][v];
                const float mn = fmaxf(mo, mx);
                const float sc = __expf(mo - mn);
                m_run[qf][v] = mn;
                float rs = 0.0f;
#pragma unroll
                for (int cf = 0; cf < 4; ++cf) {
                    const float p = __expf(s[qf][cf][v] - mn);
                    s[qf][cf][v] = p;
                    rs += p;
                }
#pragma unroll
                for (int msk = 1; msk < 16; msk <<= 1) rs += __shfl_xor(rs, msk);
                l_run[qf][v] = l_run[qf][v] * sc + rs;
#pragma unroll
                for (int df = 0; df < 4; ++df) o_acc[qf][df][v] *= sc;
            }
            // write P tile (bf16) into wave-private LDS, D-layout -> row-major
#pragma unroll
            for (int cf = 0; cf < 4; ++cf)
#pragma unroll
                for (int v = 0; v < 4; ++v) {
                    const int row = qf * 16 + g * 4 + v;
                    const int col = cf * 16 + r;
                    Pl[wv][row * 72 + col] = (short)f32_to_bf16(s[qf][cf][v]);
                }
        }

        // make P writes visible to own wave's reads; keep compiler from reordering
        asm volatile("s_waitcnt lgkmcnt(0)" ::: "memory");
        __builtin_amdgcn_sched_barrier(0);

        // ---- O += P @ V
#pragma unroll
        for (int kc = 0; kc < 2; ++kc) {
            s16x8 pa[2];
#pragma unroll
            for (int qf = 0; qf < 2; ++qf)
                pa[qf] = *(s16x8*)&Pl[wv][(qf * 16 + r) * 72 + kc * 32 + g * 8];
#pragma unroll
            for (int df = 0; df < 4; ++df) {
                const int dd = df * 16 + r;
                const int sw = (((dd >> 3) ^ dd) & 7) << 3;
                s16x8 vb = *(s16x8*)&VT[dd * 72 + ((kc * 32 + g * 8) ^ sw)];
#pragma unroll
                for (int qf = 0; qf < 2; ++qf)
                    o_acc[qf][df] = MFMA(pa[qf], vb, o_acc[qf][df]);
            }
        }
        __syncthreads();
    }

    // ---- finalize: O/l, write bf16 attn-out in [b, n, h*64+d] order
    const int bb = bh / 12, hh = bh % 12;
#pragma unroll
    for (int qf = 0; qf < 2; ++qf)
#pragma unroll
        for (int df = 0; df < 4; ++df)
#pragma unroll
            for (int v = 0; v < 4; ++v) {
                const int n = qb * 128 + wv * 32 + qf * 16 + g * 4 + v;
                const int col = hh * 64 + df * 16 + r;
                const float val = o_acc[qf][df][v] / l_run[qf][v];
                AO[(size_t)(bb * 2048 + n) * 768 + col] = f32_to_bf16(val);
            }
}

// ---------------------------------------------------------------------------
// Kernel 4: out = AO @ w_fc^T + b_fc   (AO bf16, w_fc fp32 -> bf16, out fp32)
// grid (32, 6), block 256.
// ---------------------------------------------------------------------------
__global__ __launch_bounds__(256) void fc_gemm(const unsigned short* __restrict__ A,
                                               const float* __restrict__ W,
                                               const float* __restrict__ bias,
                                               float* __restrict__ OUT) {
    __shared__ short As[128 * 72], Bs[128 * 72];
    const int t = threadIdx.x;
    const int lane = t & 63, wv = t >> 6;
    const int wm = (wv >> 1) * 64, wn = (wv & 1) * 64;
    const int r = lane & 15, g = lane >> 4;
    const int bm = blockIdx.x, bn = blockIdx.y;

    f32x4 acc[4][4];
#pragma unroll
    for (int i = 0; i < 4; ++i)
#pragma unroll
        for (int j = 0; j < 4; ++j) acc[i][j] = (f32x4)0.0f;

    for (int ks = 0; ks < 768; ks += 64) {
        // stage A (bf16 pass-through), 128x64
#pragma unroll
        for (int it = 0; it < 4; ++it) {
            const int row = (t >> 3) + it * 32;
            const int d0 = (t & 7) * 8;
            s16x8 av = *(const s16x8*)(A + (size_t)(bm * 128 + row) * 768 + ks + d0);
            *(s16x8*)&As[row * 72 + d0] = av;
        }
        // stage W rows (fp32 -> bf16), 128x64
#pragma unroll
        for (int it = 0; it < 2; ++it) {
            const int row = (t >> 2) + it * 64;
            const int k0 = (t & 3) * 16;
            const float* wx = W + (size_t)(bn * 128 + row) * 768 + ks + k0;
            short wb[16];
#pragma unroll
            for (int j = 0; j < 16; j += 4) {
                f32x4 wv4 = *(const f32x4*)(wx + j);
#pragma unroll
                for (int q = 0; q < 4; ++q) wb[j + q] = (short)f32_to_bf16(wv4[q]);
            }
            *(s16x8*)&Bs[row * 72 + k0]     = *(s16x8*)&wb[0];
            *(s16x8*)&Bs[row * 72 + k0 + 8] = *(s16x8*)&wb[8];
        }
        __syncthreads();

#pragma unroll
        for (int kc = 0; kc < 2; ++kc) {
            const int koff = kc * 32 + g * 8;
            s16x8 a[4], b[4];
#pragma unroll
            for (int mf = 0; mf < 4; ++mf) a[mf] = *(s16x8*)&As[(wm + mf * 16 + r) * 72 + koff];
#pragma unroll
            for (int nf = 0; nf < 4; ++nf) b[nf] = *(s16x8*)&Bs[(wn + nf * 16 + r) * 72 + koff];
#pragma unroll
            for (int mf = 0; mf < 4; ++mf)
#pragma unroll
                for (int nf = 0; nf < 4; ++nf)
                    acc[mf][nf] = MFMA(a[mf], b[nf], acc[mf][nf]);
        }
        __syncthreads();
    }

#pragma unroll
    for (int nf = 0; nf < 4; ++nf) {
        const int col = bn * 128 + wn + nf * 16 + r;
        const float bv = bias[col];
#pragma unroll
        for (int mf = 0; mf < 4; ++mf) {
            const int row = bm * 128 + wm + mf * 16 + g * 4;
#pragma unroll
            for (int v = 0; v < 4; ++v)
                OUT[(size_t)(row + v) * 768 + col] = acc[mf][nf][v] + bv;
        }
    }
}

// ---------------------------------------------------------------------------
extern "C" void kernel_launch(void* const* d_in, const int* in_sizes, int n_in,
                              void* d_out, int out_size, void* d_ws, size_t ws_size,
                              hipStream_t stream) {
    (void)in_sizes; (void)n_in; (void)out_size; (void)ws_size;
    const float* x     = (const float*)d_in[0];   // [2,2048,768]
    const float* w_qkv = (const float*)d_in[1];   // [2304,768]
    const float* w_fc  = (const float*)d_in[2];   // [768,768]
    const float* b_fc  = (const float*)d_in[3];   // [768]
    float* out = (float*)d_out;                   // [2,2048,768] fp32

    char* ws = (char*)d_ws;
    float* qkv = (float*)ws;                                   // 37,748,736 B
    unsigned short* Qh = (unsigned short*)(ws + 37748736);     // 6,291,456 B each
    unsigned short* Ql = Qh + 3145728;
    unsigned short* Kh = Ql + 3145728;
    unsigned short* Kl = Kh + 3145728;
    unsigned short* Vb = Kl + 3145728;
    unsigned short* AO = Vb + 3145728;                         // total 75,497,472 B

    qkv_gemm<<<dim3(32, 18), 256, 0, stream>>>(x, w_qkv, qkv);
    permute_split<<<36864, 256, 0, stream>>>(qkv, Qh, Ql, Kh, Kl, Vb);
    attn_kernel<<<384, 256, 0, stream>>>(Qh, Ql, Kh, Kl, Vb, AO);
    fc_gemm<<<dim3(32, 6), 256, 0, stream>>>(AO, w_fc, b_fc, out);
}

// Round 3
// 212.190 us; speedup vs baseline: 1.3422x; 1.3422x over previous
//
#include <hip/hip_runtime.h>
#include <stdint.h>

typedef float f32x4 __attribute__((ext_vector_type(4)));
typedef short s16x8 __attribute__((ext_vector_type(8)));

#define MFMA(a, b, c) __builtin_amdgcn_mfma_f32_16x16x32_bf16((a), (b), (c), 0, 0, 0)

__device__ __forceinline__ unsigned short f32_to_bf16(float f) {
    union { float f; uint32_t u; } v; v.f = f;
    uint32_t r = v.u + 0x7FFFu + ((v.u >> 16) & 1u);
    return (unsigned short)(r >> 16);
}
__device__ __forceinline__ float bf16_to_f32(unsigned short h) {
    union { float f; uint32_t u; } v; v.u = ((uint32_t)h) << 16;
    return v.f;
}

typedef __attribute__((address_space(1))) const uint32_t gu32;
typedef __attribute__((address_space(3))) uint32_t lu32;
__device__ __forceinline__ void gload_lds16(const void* g, void* l) {
    __builtin_amdgcn_global_load_lds((gu32*)g, (lu32*)l, 16, 0, 0);
}

// ---------------------------------------------------------------------------
// Kernel 1: split fp32 inputs into bf16 hi/lo.
//  X [4096,768] -> Xh, Xl (row-linear)
//  w_qkv [2304,768] -> Wh, Wl with ROW PERMUTATION: orig row c*768+d*12+h is
//    stored at cp = c*768 + h*64 + d, so qkv GEMM output cols are (c,h,d).
//  w_fc [768,768] -> Wfb (bf16 hi only)
// grid 2688 x 256 (= 688128 threads, 8 floats each, exact).
// ---------------------------------------------------------------------------
__global__ void split_inputs(const float* __restrict__ X, const float* __restrict__ Wq,
                             const float* __restrict__ Wf,
                             unsigned short* __restrict__ Xh, unsigned short* __restrict__ Xl,
                             unsigned short* __restrict__ Wh, unsigned short* __restrict__ Wl,
                             unsigned short* __restrict__ Wfb) {
    const int tid = blockIdx.x * 256 + threadIdx.x;
    if (tid < 393216) {                       // X: 3,145,728 floats
        const float* s = X + (size_t)tid * 8;
        short hi[8], lo[8];
#pragma unroll
        for (int j = 0; j < 8; j += 4) {
            f32x4 v = *(const f32x4*)(s + j);
#pragma unroll
            for (int q = 0; q < 4; ++q) {
                unsigned short h = f32_to_bf16(v[q]);
                hi[j + q] = (short)h;
                lo[j + q] = (short)f32_to_bf16(v[q] - bf16_to_f32(h));
            }
        }
        *(s16x8*)(Xh + (size_t)tid * 8) = *(s16x8*)hi;
        *(s16x8*)(Xl + (size_t)tid * 8) = *(s16x8*)lo;
    } else if (tid < 614400) {                // w_qkv: 1,769,472 floats
        const int t2 = tid - 393216;
        const int row = t2 / 96;
        const int k = (t2 % 96) * 8;
        const int c = row / 768;
        const int rem = row - c * 768;
        const int d = rem / 12;
        const int h2 = rem - d * 12;
        const int cp = c * 768 + h2 * 64 + d;
        const float* s = Wq + (size_t)row * 768 + k;
        short hi[8], lo[8];
#pragma unroll
        for (int j = 0; j < 8; j += 4) {
            f32x4 v = *(const f32x4*)(s + j);
#pragma unroll
            for (int q = 0; q < 4; ++q) {
                unsigned short h = f32_to_bf16(v[q]);
                hi[j + q] = (short)h;
                lo[j + q] = (short)f32_to_bf16(v[q] - bf16_to_f32(h));
            }
        }
        *(s16x8*)(Wh + (size_t)cp * 768 + k) = *(s16x8*)hi;
        *(s16x8*)(Wl + (size_t)cp * 768 + k) = *(s16x8*)lo;
    } else {                                  // w_fc: 589,824 floats
        const int t2 = tid - 614400;
        const float* s = Wf + (size_t)t2 * 8;
        short hi[8];
#pragma unroll
        for (int j = 0; j < 8; j += 4) {
            f32x4 v = *(const f32x4*)(s + j);
#pragma unroll
            for (int q = 0; q < 4; ++q) hi[j + q] = (short)f32_to_bf16(v[q]);
        }
        *(s16x8*)(Wfb + (size_t)t2 * 8) = *(s16x8*)hi;
    }
}

// ---------------------------------------------------------------------------
// Kernel 2: qkv GEMM, split-bf16 (3 MFMA for Q/K cols, 1 for V cols), staging
// via global_load_lds (wave-UNIFORM LDS base + per-lane global src, m97
// pattern). Epilogue writes per-head Qh/Ql (x8 temperature), Kh/Kl, Vb.
// grid (32, 18), block 256.
// ---------------------------------------------------------------------------
__global__ __launch_bounds__(256) void qkv_gemm(
    const unsigned short* __restrict__ Xh, const unsigned short* __restrict__ Xl,
    const unsigned short* __restrict__ Wh, const unsigned short* __restrict__ Wl,
    unsigned short* __restrict__ Qh, unsigned short* __restrict__ Ql,
    unsigned short* __restrict__ Kh, unsigned short* __restrict__ Kl,
    unsigned short* __restrict__ Vb) {
    __shared__ unsigned short Ah[128 * 32], Al[128 * 32], Bh[128 * 32], Bl[128 * 32];
    const int t = threadIdx.x;
    const int lane = t & 63, wv = t >> 6;
    const int wm = (wv >> 1) * 64, wn = (wv & 1) * 64;
    const int r = lane & 15, g = lane >> 4;
    const int bm = blockIdx.x, bn = blockIdx.y;
    const bool full = (bn < 12);   // Q/K need hi/lo split; V is bf16-tolerant

    // lane -> (row within 16-row chunk, k offset) matching LDS base+lane*16B
    const int lrow = lane >> 2;
    const int lk = (lane & 3) * 8;

    f32x4 acc[4][4];
#pragma unroll
    for (int i = 0; i < 4; ++i)
#pragma unroll
        for (int j = 0; j < 4; ++j) acc[i][j] = (f32x4)0.0f;

    for (int ks = 0; ks < 768; ks += 32) {
#pragma unroll
        for (int hh = 0; hh < 2; ++hh) {
            const int ii = wv * 2 + hh;                 // wave-uniform chunk id
            const int grow = ii * 16 + lrow;
            const size_t ga = (size_t)(bm * 128 + grow) * 768 + ks + lk;
            const size_t gb = (size_t)(bn * 128 + grow) * 768 + ks + lk;
            const int lbase = ii * 512;                  // wave-uniform LDS base
            gload_lds16(Xh + ga, &Ah[lbase]);
            gload_lds16(Wh + gb, &Bh[lbase]);
            if (full) {
                gload_lds16(Xl + ga, &Al[lbase]);
                gload_lds16(Wl + gb, &Bl[lbase]);
            }
        }
        __syncthreads();

        s16x8 a_h[4], b_h[4];
#pragma unroll
        for (int mf = 0; mf < 4; ++mf) a_h[mf] = *(s16x8*)&Ah[(wm + mf * 16 + r) * 32 + g * 8];
#pragma unroll
        for (int nf = 0; nf < 4; ++nf) b_h[nf] = *(s16x8*)&Bh[(wn + nf * 16 + r) * 32 + g * 8];
        if (full) {
            s16x8 a_l[4], b_l[4];
#pragma unroll
            for (int mf = 0; mf < 4; ++mf) a_l[mf] = *(s16x8*)&Al[(wm + mf * 16 + r) * 32 + g * 8];
#pragma unroll
            for (int nf = 0; nf < 4; ++nf) b_l[nf] = *(s16x8*)&Bl[(wn + nf * 16 + r) * 32 + g * 8];
#pragma unroll
            for (int mf = 0; mf < 4; ++mf)
#pragma unroll
                for (int nf = 0; nf < 4; ++nf) {
                    acc[mf][nf] = MFMA(a_h[mf], b_h[nf], acc[mf][nf]);
                    acc[mf][nf] = MFMA(a_h[mf], b_l[nf], acc[mf][nf]);
                    acc[mf][nf] = MFMA(a_l[mf], b_h[nf], acc[mf][nf]);
                }
        } else {
#pragma unroll
            for (int mf = 0; mf < 4; ++mf)
#pragma unroll
                for (int nf = 0; nf < 4; ++nf)
                    acc[mf][nf] = MFMA(a_h[mf], b_h[nf], acc[mf][nf]);
        }
        __syncthreads();
    }

    // epilogue: col = c*768 + h*64 + d (thanks to W row permutation)
    const int comp = bn / 6;
#pragma unroll
    for (int mf = 0; mf < 4; ++mf)
#pragma unroll
        for (int nf = 0; nf < 4; ++nf) {
            const int col = bn * 128 + wn + nf * 16 + r;
            const int h = (col >> 6) % 12;
            const int d = col & 63;
#pragma unroll
            for (int v = 0; v < 4; ++v) {
                const int row = bm * 128 + wm + mf * 16 + g * 4 + v;
                const int b = row >> 11, n = row & 2047;
                const size_t dest = ((size_t)(b * 12 + h) * 2048 + n) * 64 + d;
                float val = acc[mf][nf][v];
                if (comp == 0) {
                    val *= 8.0f;  // fold temperature (reference MULTIPLIES by sqrt(d_k))
                    unsigned short hi = f32_to_bf16(val);
                    Qh[dest] = hi;
                    Ql[dest] = f32_to_bf16(val - bf16_to_f32(hi));
                } else if (comp == 1) {
                    unsigned short hi = f32_to_bf16(val);
                    Kh[dest] = hi;
                    Kl[dest] = f32_to_bf16(val - bf16_to_f32(hi));
                } else {
                    Vb[dest] = f32_to_bf16(val);
                }
            }
        }
}

// ---------------------------------------------------------------------------
// Kernel 3: flash attention. Block = 64 Q rows (4 waves x 16 rows), KV tiles
// of 64. grid 24*32 = 768 blocks. LDS 36 KB. P tile is [16 rows][64 cols]
// -> stride 72 (>= 64 + pad). (R1 bug: stride 40 < 64 aliased P rows.)
// ---------------------------------------------------------------------------
__global__ __launch_bounds__(256) void attn_kernel(
    const unsigned short* __restrict__ Qh, const unsigned short* __restrict__ Ql,
    const unsigned short* __restrict__ Kh, const unsigned short* __restrict__ Kl,
    const unsigned short* __restrict__ Vb, unsigned short* __restrict__ AO) {
    __shared__ short Khs[64 * 72], Kls[64 * 72], VT[64 * 72];
    __shared__ short Pl[4][16 * 72];

    const int t = threadIdx.x;
    const int lane = t & 63, wv = t >> 6;
    const int r = lane & 15, g = lane >> 4;
    const int bh = blockIdx.x >> 5;   // 0..23
    const int qb = blockIdx.x & 31;
    const size_t headoff = (size_t)bh * 2048 * 64;
    const int q0 = qb * 64 + wv * 16;

    s16x8 qh[2], ql[2];
#pragma unroll
    for (int kc = 0; kc < 2; ++kc) {
        const size_t off = headoff + (size_t)(q0 + r) * 64 + kc * 32 + g * 8;
        qh[kc] = *(const s16x8*)(Qh + off);
        ql[kc] = *(const s16x8*)(Ql + off);
    }

    f32x4 o_acc[4];
    float m_run[4], l_run[4];
#pragma unroll
    for (int df = 0; df < 4; ++df) o_acc[df] = (f32x4)0.0f;
#pragma unroll
    for (int v = 0; v < 4; ++v) { m_run[v] = -1e30f; l_run[v] = 0.0f; }

    for (int kt = 0; kt < 32; ++kt) {
#pragma unroll
        for (int it = 0; it < 2; ++it) {
            const int row = (t >> 3) + it * 32;
            const int d0 = (t & 7) * 8;
            const size_t goff = headoff + (size_t)(kt * 64 + row) * 64 + d0;
            s16x8 kh = *(const s16x8*)(Kh + goff);
            s16x8 kl = *(const s16x8*)(Kl + goff);
            s16x8 vv = *(const s16x8*)(Vb + goff);
            *(s16x8*)&Khs[row * 72 + d0] = kh;
            *(s16x8*)&Kls[row * 72 + d0] = kl;
#pragma unroll
            for (int j = 0; j < 8; ++j) {
                const int dd = d0 + j;
                const int sw = (((dd >> 3) ^ dd) & 7) << 3;
                VT[dd * 72 + (row ^ sw)] = vv[j];
            }
        }
        __syncthreads();

        // ---- S = Q K^T (3-pass split-bf16)
        f32x4 s[4];
#pragma unroll
        for (int cf = 0; cf < 4; ++cf) s[cf] = (f32x4)0.0f;
#pragma unroll
        for (int kc = 0; kc < 2; ++kc) {
            const int koff = kc * 32 + g * 8;
            s16x8 kbh[4], kbl[4];
#pragma unroll
            for (int cf = 0; cf < 4; ++cf) {
                kbh[cf] = *(s16x8*)&Khs[(cf * 16 + r) * 72 + koff];
                kbl[cf] = *(s16x8*)&Kls[(cf * 16 + r) * 72 + koff];
            }
#pragma unroll
            for (int cf = 0; cf < 4; ++cf) {
                s[cf] = MFMA(qh[kc], kbh[cf], s[cf]);
                s[cf] = MFMA(qh[kc], kbl[cf], s[cf]);
                s[cf] = MFMA(ql[kc], kbh[cf], s[cf]);
            }
        }

        // ---- online softmax (row = g*4+v)
#pragma unroll
        for (int v = 0; v < 4; ++v) {
            float mx = fmaxf(fmaxf(s[0][v], s[1][v]), fmaxf(s[2][v], s[3][v]));
#pragma unroll
            for (int msk = 1; msk < 16; msk <<= 1) mx = fmaxf(mx, __shfl_xor(mx, msk));
            const float mo = m_run[v];
            const float mn = fmaxf(mo, mx);
            const float sc = __expf(mo - mn);
            m_run[v] = mn;
            float rs = 0.0f;
#pragma unroll
            for (int cf = 0; cf < 4; ++cf) {
                const float p = __expf(s[cf][v] - mn);
                s[cf][v] = p;
                rs += p;
            }
#pragma unroll
            for (int msk = 1; msk < 16; msk <<= 1) rs += __shfl_xor(rs, msk);
            l_run[v] = l_run[v] * sc + rs;
#pragma unroll
            for (int df = 0; df < 4; ++df) o_acc[df][v] *= sc;
        }
        // P tile ([16 rows][64 cols]) to wave-private LDS, stride 72
#pragma unroll
        for (int cf = 0; cf < 4; ++cf)
#pragma unroll
            for (int v = 0; v < 4; ++v) {
                const int row = g * 4 + v;
                Pl[wv][row * 72 + cf * 16 + r] = (short)f32_to_bf16(s[cf][v]);
            }

        asm volatile("s_waitcnt lgkmcnt(0)" ::: "memory");
        __builtin_amdgcn_sched_barrier(0);

        // ---- O += P @ V
#pragma unroll
        for (int kc = 0; kc < 2; ++kc) {
            s16x8 pa = *(s16x8*)&Pl[wv][r * 72 + kc * 32 + g * 8];
#pragma unroll
            for (int df = 0; df < 4; ++df) {
                const int dd = df * 16 + r;
                const int sw = (((dd >> 3) ^ dd) & 7) << 3;
                s16x8 vb = *(s16x8*)&VT[dd * 72 + ((kc * 32 + g * 8) ^ sw)];
                o_acc[df] = MFMA(pa, vb, o_acc[df]);
            }
        }
        __syncthreads();
    }

    const int bb = bh / 12, hh = bh % 12;
#pragma unroll
    for (int df = 0; df < 4; ++df)
#pragma unroll
        for (int v = 0; v < 4; ++v) {
            const int n = q0 + g * 4 + v;
            const int col = hh * 64 + df * 16 + r;
            AO[(size_t)(bb * 2048 + n) * 768 + col] = f32_to_bf16(o_acc[df][v] / l_run[v]);
        }
}

// ---------------------------------------------------------------------------
// Kernel 4: out = AO @ Wfb^T + b_fc  (all-bf16 staging, fp32 out)
// grid (32, 6), block 256.
// ---------------------------------------------------------------------------
__global__ __launch_bounds__(256) void fc_gemm(const unsigned short* __restrict__ A,
                                               const unsigned short* __restrict__ Wfb,
                                               const float* __restrict__ bias,
                                               float* __restrict__ OUT) {
    __shared__ short As[128 * 72], Bs[128 * 72];
    const int t = threadIdx.x;
    const int lane = t & 63, wv = t >> 6;
    const int wm = (wv >> 1) * 64, wn = (wv & 1) * 64;
    const int r = lane & 15, g = lane >> 4;
    const int bm = blockIdx.x, bn = blockIdx.y;

    f32x4 acc[4][4];
#pragma unroll
    for (int i = 0; i < 4; ++i)
#pragma unroll
        for (int j = 0; j < 4; ++j) acc[i][j] = (f32x4)0.0f;

    for (int ks = 0; ks < 768; ks += 64) {
#pragma unroll
        for (int it = 0; it < 4; ++it) {
            const int row = (t >> 3) + it * 32;
            const int d0 = (t & 7) * 8;
            *(s16x8*)&As[row * 72 + d0] =
                *(const s16x8*)(A + (size_t)(bm * 128 + row) * 768 + ks + d0);
        }
#pragma unroll
        for (int it = 0; it < 2; ++it) {
            const int row = (t >> 2) + it * 64;
            const int k0 = (t & 3) * 16;
            const unsigned short* wx = Wfb + (size_t)(bn * 128 + row) * 768 + ks + k0;
            *(s16x8*)&Bs[row * 72 + k0]     = *(const s16x8*)wx;
            *(s16x8*)&Bs[row * 72 + k0 + 8] = *(const s16x8*)(wx + 8);
        }
        __syncthreads();

#pragma unroll
        for (int kc = 0; kc < 2; ++kc) {
            const int koff = kc * 32 + g * 8;
            s16x8 a[4], b[4];
#pragma unroll
            for (int mf = 0; mf < 4; ++mf) a[mf] = *(s16x8*)&As[(wm + mf * 16 + r) * 72 + koff];
#pragma unroll
            for (int nf = 0; nf < 4; ++nf) b[nf] = *(s16x8*)&Bs[(wn + nf * 16 + r) * 72 + koff];
#pragma unroll
            for (int mf = 0; mf < 4; ++mf)
#pragma unroll
                for (int nf = 0; nf < 4; ++nf)
                    acc[mf][nf] = MFMA(a[mf], b[nf], acc[mf][nf]);
        }
        __syncthreads();
    }

#pragma unroll
    for (int nf = 0; nf < 4; ++nf) {
        const int col = bn * 128 + wn + nf * 16 + r;
        const float bv = bias[col];
#pragma unroll
        for (int mf = 0; mf < 4; ++mf) {
            const int row = bm * 128 + wm + mf * 16 + g * 4;
#pragma unroll
            for (int v = 0; v < 4; ++v)
                OUT[(size_t)(row + v) * 768 + col] = acc[mf][nf][v] + bv;
        }
    }
}

// ---------------------------------------------------------------------------
extern "C" void kernel_launch(void* const* d_in, const int* in_sizes, int n_in,
                              void* d_out, int out_size, void* d_ws, size_t ws_size,
                              hipStream_t stream) {
    (void)in_sizes; (void)n_in; (void)out_size; (void)ws_size;
    const float* x     = (const float*)d_in[0];   // [2,2048,768]
    const float* w_qkv = (const float*)d_in[1];   // [2304,768]
    const float* w_fc  = (const float*)d_in[2];   // [768,768]
    const float* b_fc  = (const float*)d_in[3];   // [768]
    float* out = (float*)d_out;                   // [2,2048,768] fp32

    char* ws = (char*)d_ws;
    unsigned short* Xh  = (unsigned short*)ws;                 // 6,291,456 B
    unsigned short* Xl  = Xh + 3145728;                        // 6,291,456 B
    unsigned short* Wh  = Xl + 3145728;                        // 3,538,944 B
    unsigned short* Wl  = Wh + 1769472;                        // 3,538,944 B
    unsigned short* Wfb = Wl + 1769472;                        // 1,179,648 B
    unsigned short* Qh  = Wfb + 589824;                        // 6,291,456 B each:
    unsigned short* Ql  = Qh + 3145728;
    unsigned short* Kh  = Ql + 3145728;
    unsigned short* Kl  = Kh + 3145728;
    unsigned short* Vb  = Kl + 3145728;
    unsigned short* AO  = Vb + 3145728;                        // 6,291,456 B
    // total = 58,589,184 B

    split_inputs<<<2688, 256, 0, stream>>>(x, w_qkv, w_fc, Xh, Xl, Wh, Wl, Wfb);
    qkv_gemm<<<dim3(32, 18), 256, 0, stream>>>(Xh, Xl, Wh, Wl, Qh, Ql, Kh, Kl, Vb);
    attn_kernel<<<768, 256, 0, stream>>>(Qh, Ql, Kh, Kl, Vb, AO);
    fc_gemm<<<dim3(32, 6), 256, 0, stream>>>(AO, Wfb, b_fc, out);
}

// Round 4
// 199.241 us; speedup vs baseline: 1.4295x; 1.0650x over previous
//
#include <hip/hip_runtime.h>
#include <stdint.h>

typedef float f32x4 __attribute__((ext_vector_type(4)));
typedef short s16x8 __attribute__((ext_vector_type(8)));

#define MFMA(a, b, c) __builtin_amdgcn_mfma_f32_16x16x32_bf16((a), (b), (c), 0, 0, 0)

__device__ __forceinline__ unsigned short f32_to_bf16(float f) {
    union { float f; uint32_t u; } v; v.f = f;
    uint32_t r = v.u + 0x7FFFu + ((v.u >> 16) & 1u);
    return (unsigned short)(r >> 16);
}
__device__ __forceinline__ float bf16_to_f32(unsigned short h) {
    union { float f; uint32_t u; } v; v.u = ((uint32_t)h) << 16;
    return v.f;
}

typedef __attribute__((address_space(1))) const uint32_t gu32;
typedef __attribute__((address_space(3))) uint32_t lu32;
__device__ __forceinline__ void gload_lds16(const void* g, void* l) {
    __builtin_amdgcn_global_load_lds((gu32*)g, (lu32*)l, 16, 0, 0);
}

// K/V tile image: per (head bh, kv-tile kt) a contiguous 4096-elem (8 KB)
// buffer; elem (row, k) at  row*64 + (((k>>3) ^ (row&7)) << 3) + (k&7).
// Fragment reads hit banks 4*(g ^ (r&7)) -> 2 lanes/bank (conflict-free).
__device__ __forceinline__ size_t kv_elem(int bh, int n, int d) {
    const int kt = n >> 6, row = n & 63;
    return ((size_t)(bh * 32 + kt)) * 4096 + row * 64 + (((d >> 3) ^ (row & 7)) << 3) + (d & 7);
}

// ---------------------------------------------------------------------------
// Kernel 1: split fp32 inputs into bf16 hi/lo.  (unchanged from R3)
// ---------------------------------------------------------------------------
__global__ void split_inputs(const float* __restrict__ X, const float* __restrict__ Wq,
                             const float* __restrict__ Wf,
                             unsigned short* __restrict__ Xh, unsigned short* __restrict__ Xl,
                             unsigned short* __restrict__ Wh, unsigned short* __restrict__ Wl,
                             unsigned short* __restrict__ Wfb) {
    const int tid = blockIdx.x * 256 + threadIdx.x;
    if (tid < 393216) {                       // X: 3,145,728 floats
        const float* s = X + (size_t)tid * 8;
        short hi[8], lo[8];
#pragma unroll
        for (int j = 0; j < 8; j += 4) {
            f32x4 v = *(const f32x4*)(s + j);
#pragma unroll
            for (int q = 0; q < 4; ++q) {
                unsigned short h = f32_to_bf16(v[q]);
                hi[j + q] = (short)h;
                lo[j + q] = (short)f32_to_bf16(v[q] - bf16_to_f32(h));
            }
        }
        *(s16x8*)(Xh + (size_t)tid * 8) = *(s16x8*)hi;
        *(s16x8*)(Xl + (size_t)tid * 8) = *(s16x8*)lo;
    } else if (tid < 614400) {                // w_qkv: row c*768+d*12+h -> cp=c*768+h*64+d
        const int t2 = tid - 393216;
        const int row = t2 / 96;
        const int k = (t2 % 96) * 8;
        const int c = row / 768;
        const int rem = row - c * 768;
        const int d = rem / 12;
        const int h2 = rem - d * 12;
        const int cp = c * 768 + h2 * 64 + d;
        const float* s = Wq + (size_t)row * 768 + k;
        short hi[8], lo[8];
#pragma unroll
        for (int j = 0; j < 8; j += 4) {
            f32x4 v = *(const f32x4*)(s + j);
#pragma unroll
            for (int q = 0; q < 4; ++q) {
                unsigned short h = f32_to_bf16(v[q]);
                hi[j + q] = (short)h;
                lo[j + q] = (short)f32_to_bf16(v[q] - bf16_to_f32(h));
            }
        }
        *(s16x8*)(Wh + (size_t)cp * 768 + k) = *(s16x8*)hi;
        *(s16x8*)(Wl + (size_t)cp * 768 + k) = *(s16x8*)lo;
    } else {                                  // w_fc
        const int t2 = tid - 614400;
        const float* s = Wf + (size_t)t2 * 8;
        short hi[8];
#pragma unroll
        for (int j = 0; j < 8; j += 4) {
            f32x4 v = *(const f32x4*)(s + j);
#pragma unroll
            for (int q = 0; q < 4; ++q) hi[j + q] = (short)f32_to_bf16(v[q]);
        }
        *(s16x8*)(Wfb + (size_t)t2 * 8) = *(s16x8*)hi;
    }
}

// ---------------------------------------------------------------------------
// Kernel 2: qkv GEMM (split-bf16; V cols 1 MFMA). Epilogue: Q linear (x8),
// K hi/lo -> tiled+swizzled attn image, V -> linear per-head rows.
// grid (32, 18), block 256.
// ---------------------------------------------------------------------------
__global__ __launch_bounds__(256) void qkv_gemm(
    const unsigned short* __restrict__ Xh, const unsigned short* __restrict__ Xl,
    const unsigned short* __restrict__ Wh, const unsigned short* __restrict__ Wl,
    unsigned short* __restrict__ Qh, unsigned short* __restrict__ Ql,
    unsigned short* __restrict__ Khg, unsigned short* __restrict__ Klg,
    unsigned short* __restrict__ Vb) {
    __shared__ unsigned short Ah[128 * 32], Al[128 * 32], Bh[128 * 32], Bl[128 * 32];
    const int t = threadIdx.x;
    const int lane = t & 63, wv = t >> 6;
    const int wm = (wv >> 1) * 64, wn = (wv & 1) * 64;
    const int r = lane & 15, g = lane >> 4;
    const int bm = blockIdx.x, bn = blockIdx.y;
    const bool full = (bn < 12);

    const int lrow = lane >> 2;
    const int lk = (lane & 3) * 8;

    f32x4 acc[4][4];
#pragma unroll
    for (int i = 0; i < 4; ++i)
#pragma unroll
        for (int j = 0; j < 4; ++j) acc[i][j] = (f32x4)0.0f;

    for (int ks = 0; ks < 768; ks += 32) {
#pragma unroll
        for (int hh = 0; hh < 2; ++hh) {
            const int ii = wv * 2 + hh;
            const int grow = ii * 16 + lrow;
            const size_t ga = (size_t)(bm * 128 + grow) * 768 + ks + lk;
            const size_t gb = (size_t)(bn * 128 + grow) * 768 + ks + lk;
            const int lbase = ii * 512;
            gload_lds16(Xh + ga, &Ah[lbase]);
            gload_lds16(Wh + gb, &Bh[lbase]);
            if (full) {
                gload_lds16(Xl + ga, &Al[lbase]);
                gload_lds16(Wl + gb, &Bl[lbase]);
            }
        }
        __syncthreads();

        s16x8 a_h[4], b_h[4];
#pragma unroll
        for (int mf = 0; mf < 4; ++mf) a_h[mf] = *(s16x8*)&Ah[(wm + mf * 16 + r) * 32 + g * 8];
#pragma unroll
        for (int nf = 0; nf < 4; ++nf) b_h[nf] = *(s16x8*)&Bh[(wn + nf * 16 + r) * 32 + g * 8];
        if (full) {
            s16x8 a_l[4], b_l[4];
#pragma unroll
            for (int mf = 0; mf < 4; ++mf) a_l[mf] = *(s16x8*)&Al[(wm + mf * 16 + r) * 32 + g * 8];
#pragma unroll
            for (int nf = 0; nf < 4; ++nf) b_l[nf] = *(s16x8*)&Bl[(wn + nf * 16 + r) * 32 + g * 8];
#pragma unroll
            for (int mf = 0; mf < 4; ++mf)
#pragma unroll
                for (int nf = 0; nf < 4; ++nf) {
                    acc[mf][nf] = MFMA(a_h[mf], b_h[nf], acc[mf][nf]);
                    acc[mf][nf] = MFMA(a_h[mf], b_l[nf], acc[mf][nf]);
                    acc[mf][nf] = MFMA(a_l[mf], b_h[nf], acc[mf][nf]);
                }
        } else {
#pragma unroll
            for (int mf = 0; mf < 4; ++mf)
#pragma unroll
                for (int nf = 0; nf < 4; ++nf)
                    acc[mf][nf] = MFMA(a_h[mf], b_h[nf], acc[mf][nf]);
        }
        __syncthreads();
    }

    const int comp = bn / 6;
#pragma unroll
    for (int mf = 0; mf < 4; ++mf)
#pragma unroll
        for (int nf = 0; nf < 4; ++nf) {
            const int col = bn * 128 + wn + nf * 16 + r;
            const int h = (col >> 6) % 12;
            const int d = col & 63;
#pragma unroll
            for (int v = 0; v < 4; ++v) {
                const int row = bm * 128 + wm + mf * 16 + g * 4 + v;
                const int b = row >> 11, n = row & 2047;
                const int bh = b * 12 + h;
                float val = acc[mf][nf][v];
                if (comp == 0) {
                    const size_t dest = ((size_t)bh * 2048 + n) * 64 + d;
                    val *= 8.0f;  // fold temperature (reference MULTIPLIES by sqrt(d_k))
                    unsigned short hi = f32_to_bf16(val);
                    Qh[dest] = hi;
                    Ql[dest] = f32_to_bf16(val - bf16_to_f32(hi));
                } else if (comp == 1) {
                    const size_t dest = kv_elem(bh, n, d);
                    unsigned short hi = f32_to_bf16(val);
                    Khg[dest] = hi;
                    Klg[dest] = f32_to_bf16(val - bf16_to_f32(hi));
                } else {
                    Vb[((size_t)bh * 2048 + n) * 64 + d] = f32_to_bf16(val);
                }
            }
        }
}

// ---------------------------------------------------------------------------
// Kernel 2b: V transpose. Vb [bh][n][d] -> VTg tiled image: per (bh,kt) 8 KB
// holding V^T (row=d, k=kv within tile, same swizzle as K). grid 768, 256 thr.
// ---------------------------------------------------------------------------
__global__ void v_transpose(const unsigned short* __restrict__ Vb,
                            unsigned short* __restrict__ VTg) {
    __shared__ unsigned short Vt[64 * 72];
    const int t = threadIdx.x;
    const int tile = blockIdx.x;              // bh*32 + kt
    const unsigned short* src = Vb + (size_t)tile * 4096;
    const int row = t >> 2, d0 = (t & 3) * 16;
    *(s16x8*)&Vt[row * 72 + d0]     = *(const s16x8*)(src + row * 64 + d0);
    *(s16x8*)&Vt[row * 72 + d0 + 8] = *(const s16x8*)(src + row * 64 + d0 + 8);
    __syncthreads();
    unsigned short* dst = VTg + (size_t)tile * 4096;
#pragma unroll
    for (int it = 0; it < 2; ++it) {
        const int c = t + it * 256;           // chunk: d = c>>3, sg = c&7
        const int d = c >> 3, sg = c & 7;
        const int kv0 = (sg ^ (d & 7)) * 8;
        s16x8 o;
#pragma unroll
        for (int j = 0; j < 8; ++j) o[j] = (short)Vt[(kv0 + j) * 72 + d];
        *(s16x8*)(dst + (size_t)c * 8) = o;   // byte c*16 = d*128 + sg*16
    }
}

// ---------------------------------------------------------------------------
// Kernel 3: flash attention. 64 Q rows/block (4 waves x 16), KV tiles of 64
// staged as straight 8 KB gload_lds memcpys of the pre-swizzled images.
// grid 768, block 256. LDS 33.8 KB.
// ---------------------------------------------------------------------------
__global__ __launch_bounds__(256) void attn_kernel(
    const unsigned short* __restrict__ Qh, const unsigned short* __restrict__ Ql,
    const unsigned short* __restrict__ Khg, const unsigned short* __restrict__ Klg,
    const unsigned short* __restrict__ VTg, unsigned short* __restrict__ AO) {
    __shared__ unsigned short Khs[4096], Kls[4096], VTs[4096];
    __shared__ unsigned short Pl[4][16 * 72];

    const int t = threadIdx.x;
    const int lane = t & 63, wv = t >> 6;
    const int r = lane & 15, g = lane >> 4;
    const int bh = blockIdx.x >> 5;   // 0..23
    const int qb = blockIdx.x & 31;
    const size_t headoff = (size_t)bh * 2048 * 64;
    const int q0 = qb * 64 + wv * 16;

    s16x8 qh[2], ql[2];
#pragma unroll
    for (int kc = 0; kc < 2; ++kc) {
        const size_t off = headoff + (size_t)(q0 + r) * 64 + kc * 32 + g * 8;
        qh[kc] = *(const s16x8*)(Qh + off);
        ql[kc] = *(const s16x8*)(Ql + off);
    }

    f32x4 o_acc[4];
    float m_run[4], l_run[4];
#pragma unroll
    for (int df = 0; df < 4; ++df) o_acc[df] = (f32x4)0.0f;
#pragma unroll
    for (int v = 0; v < 4; ++v) { m_run[v] = -1e30f; l_run[v] = 0.0f; }

    for (int kt = 0; kt < 32; ++kt) {
        // ---- stage: three 8 KB image copies (2 chunks of 1 KB per wave each)
        const size_t tb = ((size_t)bh * 32 + kt) * 4096;
#pragma unroll
        for (int c2 = 0; c2 < 2; ++c2) {
            const int c = wv * 2 + c2;
            const int go = c * 512 + lane * 8;
            gload_lds16(Khg + tb + go, &Khs[c * 512]);
            gload_lds16(Klg + tb + go, &Kls[c * 512]);
            gload_lds16(VTg + tb + go, &VTs[c * 512]);
        }
        __syncthreads();

        // ---- S = Q K^T (3-pass split-bf16), swizzled conflict-free reads
        f32x4 s[4];
#pragma unroll
        for (int cf = 0; cf < 4; ++cf) s[cf] = (f32x4)0.0f;
#pragma unroll
        for (int kc = 0; kc < 2; ++kc) {
            const int swz = (((kc * 4 + g) ^ (r & 7)) << 3);
            s16x8 kbh[4], kbl[4];
#pragma unroll
            for (int cf = 0; cf < 4; ++cf) {
                kbh[cf] = *(s16x8*)&Khs[(cf * 16 + r) * 64 + swz];
                kbl[cf] = *(s16x8*)&Kls[(cf * 16 + r) * 64 + swz];
            }
#pragma unroll
            for (int cf = 0; cf < 4; ++cf) {
                s[cf] = MFMA(qh[kc], kbh[cf], s[cf]);
                s[cf] = MFMA(qh[kc], kbl[cf], s[cf]);
                s[cf] = MFMA(ql[kc], kbh[cf], s[cf]);
            }
        }

        // ---- online softmax (row = g*4+v)
#pragma unroll
        for (int v = 0; v < 4; ++v) {
            float mx = fmaxf(fmaxf(s[0][v], s[1][v]), fmaxf(s[2][v], s[3][v]));
#pragma unroll
            for (int msk = 1; msk < 16; msk <<= 1) mx = fmaxf(mx, __shfl_xor(mx, msk));
            const float mo = m_run[v];
            const float mn = fmaxf(mo, mx);
            const float sc = __expf(mo - mn);
            m_run[v] = mn;
            float rs = 0.0f;
#pragma unroll
            for (int cf = 0; cf < 4; ++cf) {
                const float p = __expf(s[cf][v] - mn);
                s[cf][v] = p;
                rs += p;
            }
#pragma unroll
            for (int msk = 1; msk < 16; msk <<= 1) rs += __shfl_xor(rs, msk);
            l_run[v] = l_run[v] * sc + rs;
#pragma unroll
            for (int df = 0; df < 4; ++df) o_acc[df][v] *= sc;
        }
        // P tile ([16 rows][64 cols]) to wave-private LDS, stride 72
#pragma unroll
        for (int cf = 0; cf < 4; ++cf)
#pragma unroll
            for (int v = 0; v < 4; ++v) {
                const int row = g * 4 + v;
                Pl[wv][row * 72 + cf * 16 + r] = f32_to_bf16(s[cf][v]);
            }

        asm volatile("s_waitcnt lgkmcnt(0)" ::: "memory");
        __builtin_amdgcn_sched_barrier(0);

        // ---- O += P @ V   (V^T image reads, conflict-free)
#pragma unroll
        for (int kc = 0; kc < 2; ++kc) {
            s16x8 pa = *(s16x8*)&Pl[wv][r * 72 + kc * 32 + g * 8];
            const int swz = (((kc * 4 + g) ^ (r & 7)) << 3);
#pragma unroll
            for (int df = 0; df < 4; ++df) {
                s16x8 vb = *(s16x8*)&VTs[(df * 16 + r) * 64 + swz];
                o_acc[df] = MFMA(pa, vb, o_acc[df]);
            }
        }
        __syncthreads();
    }

    const int bb = bh / 12, hh = bh % 12;
#pragma unroll
    for (int df = 0; df < 4; ++df)
#pragma unroll
        for (int v = 0; v < 4; ++v) {
            const int n = q0 + g * 4 + v;
            const int col = hh * 64 + df * 16 + r;
            AO[(size_t)(bb * 2048 + n) * 768 + col] = f32_to_bf16(o_acc[df][v] / l_run[v]);
        }
}

// ---------------------------------------------------------------------------
// Kernel 4: out = AO @ Wfb^T + b_fc  (unchanged from R3)
// ---------------------------------------------------------------------------
__global__ __launch_bounds__(256) void fc_gemm(const unsigned short* __restrict__ A,
                                               const unsigned short* __restrict__ Wfb,
                                               const float* __restrict__ bias,
                                               float* __restrict__ OUT) {
    __shared__ short As[128 * 72], Bs[128 * 72];
    const int t = threadIdx.x;
    const int lane = t & 63, wv = t >> 6;
    const int wm = (wv >> 1) * 64, wn = (wv & 1) * 64;
    const int r = lane & 15, g = lane >> 4;
    const int bm = blockIdx.x, bn = blockIdx.y;

    f32x4 acc[4][4];
#pragma unroll
    for (int i = 0; i < 4; ++i)
#pragma unroll
        for (int j = 0; j < 4; ++j) acc[i][j] = (f32x4)0.0f;

    for (int ks = 0; ks < 768; ks += 64) {
#pragma unroll
        for (int it = 0; it < 4; ++it) {
            const int row = (t >> 3) + it * 32;
            const int d0 = (t & 7) * 8;
            *(s16x8*)&As[row * 72 + d0] =
                *(const s16x8*)(A + (size_t)(bm * 128 + row) * 768 + ks + d0);
        }
#pragma unroll
        for (int it = 0; it < 2; ++it) {
            const int row = (t >> 2) + it * 64;
            const int k0 = (t & 3) * 16;
            const unsigned short* wx = Wfb + (size_t)(bn * 128 + row) * 768 + ks + k0;
            *(s16x8*)&Bs[row * 72 + k0]     = *(const s16x8*)wx;
            *(s16x8*)&Bs[row * 72 + k0 + 8] = *(const s16x8*)(wx + 8);
        }
        __syncthreads();

#pragma unroll
        for (int kc = 0; kc < 2; ++kc) {
            const int koff = kc * 32 + g * 8;
            s16x8 a[4], b[4];
#pragma unroll
            for (int mf = 0; mf < 4; ++mf) a[mf] = *(s16x8*)&As[(wm + mf * 16 + r) * 72 + koff];
#pragma unroll
            for (int nf = 0; nf < 4; ++nf) b[nf] = *(s16x8*)&Bs[(wn + nf * 16 + r) * 72 + koff];
#pragma unroll
            for (int mf = 0; mf < 4; ++mf)
#pragma unroll
                for (int nf = 0; nf < 4; ++nf)
                    acc[mf][nf] = MFMA(a[mf], b[nf], acc[mf][nf]);
        }
        __syncthreads();
    }

#pragma unroll
    for (int nf = 0; nf < 4; ++nf) {
        const int col = bn * 128 + wn + nf * 16 + r;
        const float bv = bias[col];
#pragma unroll
        for (int mf = 0; mf < 4; ++mf) {
            const int row = bm * 128 + wm + mf * 16 + g * 4;
#pragma unroll
            for (int v = 0; v < 4; ++v)
                OUT[(size_t)(row + v) * 768 + col] = acc[mf][nf][v] + bv;
        }
    }
}

// ---------------------------------------------------------------------------
extern "C" void kernel_launch(void* const* d_in, const int* in_sizes, int n_in,
                              void* d_out, int out_size, void* d_ws, size_t ws_size,
                              hipStream_t stream) {
    (void)in_sizes; (void)n_in; (void)out_size; (void)ws_size;
    const float* x     = (const float*)d_in[0];   // [2,2048,768]
    const float* w_qkv = (const float*)d_in[1];   // [2304,768]
    const float* w_fc  = (const float*)d_in[2];   // [768,768]
    const float* b_fc  = (const float*)d_in[3];   // [768]
    float* out = (float*)d_out;                   // [2,2048,768] fp32

    char* ws = (char*)d_ws;
    unsigned short* Xh  = (unsigned short*)ws;                 // 6,291,456 B
    unsigned short* Xl  = Xh + 3145728;
    unsigned short* Wh  = Xl + 3145728;                        // 3,538,944 B
    unsigned short* Wl  = Wh + 1769472;
    unsigned short* Wfb = Wl + 1769472;                        // 1,179,648 B
    unsigned short* Qh  = Wfb + 589824;                        // 6,291,456 B each:
    unsigned short* Ql  = Qh + 3145728;
    unsigned short* Khg = Ql + 3145728;
    unsigned short* Klg = Khg + 3145728;
    unsigned short* Vb  = Klg + 3145728;
    unsigned short* VTg = Vb + 3145728;
    unsigned short* AO  = VTg + 3145728;                       // 6,291,456 B
    // total = 64,880,640 B

    split_inputs<<<2688, 256, 0, stream>>>(x, w_qkv, w_fc, Xh, Xl, Wh, Wl, Wfb);
    qkv_gemm<<<dim3(32, 18), 256, 0, stream>>>(Xh, Xl, Wh, Wl, Qh, Ql, Khg, Klg, Vb);
    v_transpose<<<768, 256, 0, stream>>>(Vb, VTg);
    attn_kernel<<<768, 256, 0, stream>>>(Qh, Ql, Khg, Klg, VTg, AO);
    fc_gemm<<<dim3(32, 6), 256, 0, stream>>>(AO, Wfb, b_fc, out);
}

// Round 5
// 149.389 us; speedup vs baseline: 1.9065x; 1.3337x over previous
//
#include <hip/hip_runtime.h>
#include <stdint.h>

typedef float f32x4 __attribute__((ext_vector_type(4)));
typedef _Float16 f16;
typedef f16 f16x8 __attribute__((ext_vector_type(8)));
typedef f16 f16x4 __attribute__((ext_vector_type(4)));

#define MFMA16(a, b, c) __builtin_amdgcn_mfma_f32_16x16x32_f16((a), (b), (c), 0, 0, 0)

typedef __attribute__((address_space(1))) const uint32_t gu32;
typedef __attribute__((address_space(3))) uint32_t lu32;
__device__ __forceinline__ void gload_lds16(const void* g, void* l) {
    __builtin_amdgcn_global_load_lds((gu32*)g, (lu32*)l, 16, 0, 0);
}

// K/V tile image: per (head bh, kv-tile kt) a contiguous 4096-elem (8 KB)
// buffer; elem (row, k) at  row*64 + (((k>>3) ^ (row&7)) << 3) + (k&7).
__device__ __forceinline__ size_t kv_elem(int bh, int n, int d) {
    const int kt = n >> 6, row = n & 63;
    return ((size_t)(bh * 32 + kt)) * 4096 + row * 64 + (((d >> 3) ^ (row & 7)) << 3) + (d & 7);
}

// ---------------------------------------------------------------------------
// Kernel 1: convert fp32 inputs to fp16.
//  X -> Xh + Xl (hi/lo split, exact to ~2^-22)
//  w_qkv -> Wh single fp16, rows PERMUTED: orig row c*768+d*12+h stored at
//           cp = c*768 + h*64 + d  (so qkv output cols are (comp, head, d))
//  w_fc -> Wfb single fp16
// ---------------------------------------------------------------------------
__global__ void split_inputs(const float* __restrict__ X, const float* __restrict__ Wq,
                             const float* __restrict__ Wf,
                             f16* __restrict__ Xh, f16* __restrict__ Xl,
                             f16* __restrict__ Wh, f16* __restrict__ Wfb) {
    const int tid = blockIdx.x * 256 + threadIdx.x;
    if (tid < 393216) {                       // X: 3,145,728 floats
        const float* s = X + (size_t)tid * 8;
        f16 hi[8], lo[8];
#pragma unroll
        for (int j = 0; j < 8; j += 4) {
            f32x4 v = *(const f32x4*)(s + j);
#pragma unroll
            for (int q = 0; q < 4; ++q) {
                f16 h = (f16)v[q];
                hi[j + q] = h;
                lo[j + q] = (f16)(v[q] - (float)h);
            }
        }
        *(f16x8*)(Xh + (size_t)tid * 8) = *(f16x8*)hi;
        *(f16x8*)(Xl + (size_t)tid * 8) = *(f16x8*)lo;
    } else if (tid < 614400) {                // w_qkv: 1,769,472 floats
        const int t2 = tid - 393216;
        const int row = t2 / 96;
        const int k = (t2 % 96) * 8;
        const int c = row / 768;
        const int rem = row - c * 768;
        const int d = rem / 12;
        const int h2 = rem - d * 12;
        const int cp = c * 768 + h2 * 64 + d;
        const float* s = Wq + (size_t)row * 768 + k;
        f16 hi[8];
#pragma unroll
        for (int j = 0; j < 8; j += 4) {
            f32x4 v = *(const f32x4*)(s + j);
#pragma unroll
            for (int q = 0; q < 4; ++q) hi[j + q] = (f16)v[q];
        }
        *(f16x8*)(Wh + (size_t)cp * 768 + k) = *(f16x8*)hi;
    } else {                                  // w_fc: 589,824 floats
        const int t2 = tid - 614400;
        const float* s = Wf + (size_t)t2 * 8;
        f16 hi[8];
#pragma unroll
        for (int j = 0; j < 8; j += 4) {
            f32x4 v = *(const f32x4*)(s + j);
#pragma unroll
            for (int q = 0; q < 4; ++q) hi[j + q] = (f16)v[q];
        }
        *(f16x8*)(Wfb + (size_t)t2 * 8) = *(f16x8*)hi;
    }
}

// ---------------------------------------------------------------------------
// Kernel 2: qkv GEMM, fp16: Q/K cols = 2 MFMA (x hi+lo), V cols = 1 MFMA.
// Epilogue: Q fp16 hi/lo (x8 temperature) linear; K fp16 -> swizzled image;
// V fp16 linear. grid (32, 18), block 256.
// ---------------------------------------------------------------------------
__global__ __launch_bounds__(256) void qkv_gemm(
    const f16* __restrict__ Xh, const f16* __restrict__ Xl,
    const f16* __restrict__ Wh,
    f16* __restrict__ Qh, f16* __restrict__ Ql,
    f16* __restrict__ Khg, f16* __restrict__ Vb) {
    __shared__ f16 Ah[128 * 32], Al[128 * 32], Bh[128 * 32];
    const int t = threadIdx.x;
    const int lane = t & 63, wv = t >> 6;
    const int wm = (wv >> 1) * 64, wn = (wv & 1) * 64;
    const int r = lane & 15, g = lane >> 4;
    const int bm = blockIdx.x, bn = blockIdx.y;
    const bool full = (bn < 12);   // Q/K need the x-lo pass; V doesn't

    const int lrow = lane >> 2;
    const int lk = (lane & 3) * 8;

    f32x4 acc[4][4];
#pragma unroll
    for (int i = 0; i < 4; ++i)
#pragma unroll
        for (int j = 0; j < 4; ++j) acc[i][j] = (f32x4)0.0f;

    for (int ks = 0; ks < 768; ks += 32) {
#pragma unroll
        for (int hh = 0; hh < 2; ++hh) {
            const int ii = wv * 2 + hh;
            const int grow = ii * 16 + lrow;
            const size_t ga = (size_t)(bm * 128 + grow) * 768 + ks + lk;
            const size_t gb = (size_t)(bn * 128 + grow) * 768 + ks + lk;
            const int lbase = ii * 512;                  // wave-uniform LDS base
            gload_lds16(Xh + ga, &Ah[lbase]);
            gload_lds16(Wh + gb, &Bh[lbase]);
            if (full) gload_lds16(Xl + ga, &Al[lbase]);
        }
        __syncthreads();

        f16x8 a_h[4], b[4];
#pragma unroll
        for (int mf = 0; mf < 4; ++mf) a_h[mf] = *(f16x8*)&Ah[(wm + mf * 16 + r) * 32 + g * 8];
#pragma unroll
        for (int nf = 0; nf < 4; ++nf) b[nf] = *(f16x8*)&Bh[(wn + nf * 16 + r) * 32 + g * 8];
        if (full) {
            f16x8 a_l[4];
#pragma unroll
            for (int mf = 0; mf < 4; ++mf) a_l[mf] = *(f16x8*)&Al[(wm + mf * 16 + r) * 32 + g * 8];
#pragma unroll
            for (int mf = 0; mf < 4; ++mf)
#pragma unroll
                for (int nf = 0; nf < 4; ++nf) {
                    acc[mf][nf] = MFMA16(a_h[mf], b[nf], acc[mf][nf]);
                    acc[mf][nf] = MFMA16(a_l[mf], b[nf], acc[mf][nf]);
                }
        } else {
#pragma unroll
            for (int mf = 0; mf < 4; ++mf)
#pragma unroll
                for (int nf = 0; nf < 4; ++nf)
                    acc[mf][nf] = MFMA16(a_h[mf], b[nf], acc[mf][nf]);
        }
        __syncthreads();
    }

    const int comp = bn / 6;
#pragma unroll
    for (int mf = 0; mf < 4; ++mf)
#pragma unroll
        for (int nf = 0; nf < 4; ++nf) {
            const int col = bn * 128 + wn + nf * 16 + r;
            const int h = (col >> 6) % 12;
            const int d = col & 63;
#pragma unroll
            for (int v = 0; v < 4; ++v) {
                const int row = bm * 128 + wm + mf * 16 + g * 4 + v;
                const int b2 = row >> 11, n = row & 2047;
                const int bh = b2 * 12 + h;
                float val = acc[mf][nf][v];
                if (comp == 0) {
                    const size_t dest = ((size_t)bh * 2048 + n) * 64 + d;
                    val *= 8.0f;  // fold temperature (reference MULTIPLIES by sqrt(d_k))
                    f16 hi = (f16)val;
                    Qh[dest] = hi;
                    Ql[dest] = (f16)(val - (float)hi);
                } else if (comp == 1) {
                    Khg[kv_elem(bh, n, d)] = (f16)val;
                } else {
                    Vb[((size_t)bh * 2048 + n) * 64 + d] = (f16)val;
                }
            }
        }
}

// ---------------------------------------------------------------------------
// Kernel 2b: V transpose into the tiled+swizzled image. grid 768, block 256.
// ---------------------------------------------------------------------------
__global__ void v_transpose(const f16* __restrict__ Vb, f16* __restrict__ VTg) {
    __shared__ f16 Vt[64 * 72];
    const int t = threadIdx.x;
    const int tile = blockIdx.x;              // bh*32 + kt
    const f16* src = Vb + (size_t)tile * 4096;
    const int row = t >> 2, d0 = (t & 3) * 16;
    *(f16x8*)&Vt[row * 72 + d0]     = *(const f16x8*)(src + row * 64 + d0);
    *(f16x8*)&Vt[row * 72 + d0 + 8] = *(const f16x8*)(src + row * 64 + d0 + 8);
    __syncthreads();
    f16* dst = VTg + (size_t)tile * 4096;
#pragma unroll
    for (int it = 0; it < 2; ++it) {
        const int c = t + it * 256;           // chunk: d = c>>3, sg = c&7
        const int d = c >> 3, sg = c & 7;
        const int kv0 = (sg ^ (d & 7)) * 8;
        f16 o[8];
#pragma unroll
        for (int j = 0; j < 8; ++j) o[j] = Vt[(kv0 + j) * 72 + d];
        *(f16x8*)(dst + (size_t)c * 8) = *(f16x8*)o;
    }
}

// ---------------------------------------------------------------------------
// Kernel 3: flash attention, SWAPPED QK^T (S^T = mfma(K, Q)): lane (r,g)
// holds S[q=r][k=cf*16+g*4+v] -> in-register row reduction + 2 shfl.
// 64 Q rows/block (4 waves x 16). grid 768, block 256. LDS 25.2 KB.
// ---------------------------------------------------------------------------
__global__ __launch_bounds__(256) void attn_kernel(
    const f16* __restrict__ Qh, const f16* __restrict__ Ql,
    const f16* __restrict__ Khg, const f16* __restrict__ VTg,
    f16* __restrict__ AO) {
    __shared__ f16 Khs[4096], VTs[4096];
    __shared__ f16 Pl[4][16 * 72];

    const int t = threadIdx.x;
    const int lane = t & 63, wv = t >> 6;
    const int r = lane & 15, g = lane >> 4;
    const int bh = blockIdx.x >> 5;   // 0..23
    const int qb = blockIdx.x & 31;
    const size_t headoff = (size_t)bh * 2048 * 64;
    const int q0 = qb * 64 + wv * 16;

    // Q fragments (B-operand): lane (r,g) holds Q[q0+r][kc*32+g*8 .. +7]
    f16x8 qh[2], ql[2];
#pragma unroll
    for (int kc = 0; kc < 2; ++kc) {
        const size_t off = headoff + (size_t)(q0 + r) * 64 + kc * 32 + g * 8;
        qh[kc] = *(const f16x8*)(Qh + off);
        ql[kc] = *(const f16x8*)(Ql + off);
    }

    f32x4 o_acc[4];
    float m_run = -1e30f, l_run = 0.0f;   // stats for row q0 + r (per lane)
#pragma unroll
    for (int df = 0; df < 4; ++df) o_acc[df] = (f32x4)0.0f;

    for (int kt = 0; kt < 32; ++kt) {
        // ---- stage K and V^T images (8 KB each, 4 gloads/wave)
        const size_t tb = ((size_t)bh * 32 + kt) * 4096;
#pragma unroll
        for (int c2 = 0; c2 < 2; ++c2) {
            const int c = wv * 2 + c2;
            const int go = c * 512 + lane * 8;
            gload_lds16(Khg + tb + go, &Khs[c * 512]);
            gload_lds16(VTg + tb + go, &VTs[c * 512]);
        }
        __syncthreads();

        // ---- S^T = K Q^T : lane (r,g) gets S[q=r][k=cf*16+g*4+v]
        f32x4 s[4];
#pragma unroll
        for (int cf = 0; cf < 4; ++cf) s[cf] = (f32x4)0.0f;
#pragma unroll
        for (int kc = 0; kc < 2; ++kc) {
            const int swz = (((kc * 4 + g) ^ (r & 7)) << 3);
            f16x8 ka[4];
#pragma unroll
            for (int cf = 0; cf < 4; ++cf) ka[cf] = *(f16x8*)&Khs[(cf * 16 + r) * 64 + swz];
#pragma unroll
            for (int cf = 0; cf < 4; ++cf) {
                s[cf] = MFMA16(ka[cf], qh[kc], s[cf]);
                s[cf] = MFMA16(ka[cf], ql[kc], s[cf]);
            }
        }

        // ---- online softmax, row r owned by this lane (16 vals in-reg)
        float mx = -1e30f;
#pragma unroll
        for (int cf = 0; cf < 4; ++cf)
#pragma unroll
            for (int v = 0; v < 4; ++v) mx = fmaxf(mx, s[cf][v]);
        mx = fmaxf(mx, __shfl_xor(mx, 16));
        mx = fmaxf(mx, __shfl_xor(mx, 32));
        const float mn = fmaxf(m_run, mx);
        const float sc = __expf(m_run - mn);
        m_run = mn;
        float rs = 0.0f;
        f16 p16[4][4];
#pragma unroll
        for (int cf = 0; cf < 4; ++cf)
#pragma unroll
            for (int v = 0; v < 4; ++v) {
                const float p = __expf(s[cf][v] - mn);
                rs += p;
                p16[cf][v] = (f16)p;
            }
        rs += __shfl_xor(rs, 16);
        rs += __shfl_xor(rs, 32);
        l_run = l_run * sc + rs;

        // rescale o_acc: its rows are g*4+v -> fetch sc from lane g*4+v
#pragma unroll
        for (int v = 0; v < 4; ++v) {
            const float scv = __shfl(sc, g * 4 + v);
#pragma unroll
            for (int df = 0; df < 4; ++df) o_acc[df][v] *= scv;
        }

        // ---- write P (row q=r, cols cf*16+g*4 .. +3) as b64 stores
#pragma unroll
        for (int cf = 0; cf < 4; ++cf)
            *(f16x4*)&Pl[wv][r * 72 + cf * 16 + g * 4] = *(f16x4*)p16[cf];

        asm volatile("s_waitcnt lgkmcnt(0)" ::: "memory");
        __builtin_amdgcn_sched_barrier(0);

        // ---- O += P @ V
#pragma unroll
        for (int kc = 0; kc < 2; ++kc) {
            f16x8 pa = *(f16x8*)&Pl[wv][r * 72 + kc * 32 + g * 8];
            const int swz = (((kc * 4 + g) ^ (r & 7)) << 3);
#pragma unroll
            for (int df = 0; df < 4; ++df) {
                f16x8 vb = *(f16x8*)&VTs[(df * 16 + r) * 64 + swz];
                o_acc[df] = MFMA16(pa, vb, o_acc[df]);
            }
        }
        __syncthreads();
    }

    // ---- finalize: rows of o_acc are g*4+v; l for that row sits at lane g*4+v
    const int bb = bh / 12, hh = bh % 12;
#pragma unroll
    for (int v = 0; v < 4; ++v) {
        const float lv = __shfl(l_run, g * 4 + v);
        const float inv = 1.0f / lv;
        const int n = q0 + g * 4 + v;
#pragma unroll
        for (int df = 0; df < 4; ++df) {
            const int col = hh * 64 + df * 16 + r;
            AO[(size_t)(bb * 2048 + n) * 768 + col] = (f16)(o_acc[df][v] * inv);
        }
    }
}

// ---------------------------------------------------------------------------
// Kernel 4: out = AO @ Wfb^T + b_fc  (fp16 in, fp32 out). grid (32,6).
// ---------------------------------------------------------------------------
__global__ __launch_bounds__(256) void fc_gemm(const f16* __restrict__ A,
                                               const f16* __restrict__ Wfb,
                                               const float* __restrict__ bias,
                                               float* __restrict__ OUT) {
    __shared__ f16 As[128 * 72], Bs[128 * 72];
    const int t = threadIdx.x;
    const int lane = t & 63, wv = t >> 6;
    const int wm = (wv >> 1) * 64, wn = (wv & 1) * 64;
    const int r = lane & 15, g = lane >> 4;
    const int bm = blockIdx.x, bn = blockIdx.y;

    f32x4 acc[4][4];
#pragma unroll
    for (int i = 0; i < 4; ++i)
#pragma unroll
        for (int j = 0; j < 4; ++j) acc[i][j] = (f32x4)0.0f;

    for (int ks = 0; ks < 768; ks += 64) {
#pragma unroll
        for (int it = 0; it < 4; ++it) {
            const int row = (t >> 3) + it * 32;
            const int d0 = (t & 7) * 8;
            *(f16x8*)&As[row * 72 + d0] =
                *(const f16x8*)(A + (size_t)(bm * 128 + row) * 768 + ks + d0);
        }
#pragma unroll
        for (int it = 0; it < 2; ++it) {
            const int row = (t >> 2) + it * 64;
            const int k0 = (t & 3) * 16;
            const f16* wx = Wfb + (size_t)(bn * 128 + row) * 768 + ks + k0;
            *(f16x8*)&Bs[row * 72 + k0]     = *(const f16x8*)wx;
            *(f16x8*)&Bs[row * 72 + k0 + 8] = *(const f16x8*)(wx + 8);
        }
        __syncthreads();

#pragma unroll
        for (int kc = 0; kc < 2; ++kc) {
            const int koff = kc * 32 + g * 8;
            f16x8 a[4], b[4];
#pragma unroll
            for (int mf = 0; mf < 4; ++mf) a[mf] = *(f16x8*)&As[(wm + mf * 16 + r) * 72 + koff];
#pragma unroll
            for (int nf = 0; nf < 4; ++nf) b[nf] = *(f16x8*)&Bs[(wn + nf * 16 + r) * 72 + koff];
#pragma unroll
            for (int mf = 0; mf < 4; ++mf)
#pragma unroll
                for (int nf = 0; nf < 4; ++nf)
                    acc[mf][nf] = MFMA16(a[mf], b[nf], acc[mf][nf]);
        }
        __syncthreads();
    }

#pragma unroll
    for (int nf = 0; nf < 4; ++nf) {
        const int col = bn * 128 + wn + nf * 16 + r;
        const float bv = bias[col];
#pragma unroll
        for (int mf = 0; mf < 4; ++mf) {
            const int row = bm * 128 + wm + mf * 16 + g * 4;
#pragma unroll
            for (int v = 0; v < 4; ++v)
                OUT[(size_t)(row + v) * 768 + col] = acc[mf][nf][v] + bv;
        }
    }
}

// ---------------------------------------------------------------------------
extern "C" void kernel_launch(void* const* d_in, const int* in_sizes, int n_in,
                              void* d_out, int out_size, void* d_ws, size_t ws_size,
                              hipStream_t stream) {
    (void)in_sizes; (void)n_in; (void)out_size; (void)ws_size;
    const float* x     = (const float*)d_in[0];   // [2,2048,768]
    const float* w_qkv = (const float*)d_in[1];   // [2304,768]
    const float* w_fc  = (const float*)d_in[2];   // [768,768]
    const float* b_fc  = (const float*)d_in[3];   // [768]
    float* out = (float*)d_out;                   // [2,2048,768] fp32

    char* ws = (char*)d_ws;
    f16* Xh  = (f16*)ws;                         // 3,145,728 elems each (6 MB):
    f16* Xl  = Xh + 3145728;
    f16* Qh  = Xl + 3145728;
    f16* Ql  = Qh + 3145728;
    f16* Khg = Ql + 3145728;
    f16* Vb  = Khg + 3145728;
    f16* VTg = Vb + 3145728;
    f16* AO  = VTg + 3145728;
    f16* Wh  = AO + 3145728;                     // 1,769,472 elems
    f16* Wfb = Wh + 1769472;                     // 589,824 elems
    // total = 55,050,240 B

    split_inputs<<<2688, 256, 0, stream>>>(x, w_qkv, w_fc, Xh, Xl, Wh, Wfb);
    qkv_gemm<<<dim3(32, 18), 256, 0, stream>>>(Xh, Xl, Wh, Qh, Ql, Khg, Vb);
    v_transpose<<<768, 256, 0, stream>>>(Vb, VTg);
    attn_kernel<<<768, 256, 0, stream>>>(Qh, Ql, Khg, VTg, AO);
    fc_gemm<<<dim3(32, 6), 256, 0, stream>>>(AO, Wfb, b_fc, out);
}